// Round 1
// 638.376 us; speedup vs baseline: 1.1903x; 1.1903x over previous
//
#include <hip/hip_runtime.h>
#include <math.h>

namespace {
constexpr int B = 16, T = 1024, F = 1024, H = 16, D = 64;
constexpr int NT = B * T;            // 16384 token rows
constexpr int QKV_COLS = 3 * F;      // 3072

// workspace layout (bytes). Proven ws_size >= 182,452,224.
constexpr size_t XHI_OFF = 0;                    // bf16 x hi      33,554,432
constexpr size_t XLO_OFF = 33554432;             // bf16 x lo      33,554,432
constexpr size_t WAH_OFF = 67108864;             // bf16 Wa^T hi    6,291,456
constexpr size_t WVL_OFF = 73400320;             // bf16 Wv^T lo    2,097,152
constexpr size_t QB_OFF  = 75497472;             // bf16 q         33,554,432
constexpr size_t KB_OFF  = 109051904;            // bf16 k         33,554,432
constexpr size_t SB_OFF  = 142606336;            // f32 s           4,194,304
constexpr size_t AB_OFF  = 146800640;            // bf16 a         33,554,432
constexpr size_t WPB_OFF = 180355072;            // bf16 Wp^T       2,097,152
// overlays: vb (f32, 67MB) = QB..KB span (q,k dead after score);
//           wraw (f32, 67MB) = XHI..XLO span (x dead after v GEMM);
//           sp partial sums (f32, 256KB) = WVL span (Wv_lo dead after v GEMM)
constexpr size_t VB_OFF   = QB_OFF;
constexpr size_t WRAW_OFF = XHI_OFF;
constexpr size_t SP_OFF   = WVL_OFF;
}

typedef __attribute__((ext_vector_type(8))) __bf16 bf16x8;
typedef __attribute__((ext_vector_type(4))) float f32x4;

__device__ __forceinline__ unsigned short f2bf(float f) {
  unsigned u = __builtin_bit_cast(unsigned, f);
  u += 0x7FFFu + ((u >> 16) & 1u);
  return (unsigned short)(u >> 16);
}
__device__ __forceinline__ float bf2f(unsigned short s) {
  return __builtin_bit_cast(float, (unsigned)s << 16);
}
__device__ __forceinline__ void gld16(const unsigned short* g, unsigned short* l) {
  __builtin_amdgcn_global_load_lds(
      (const __attribute__((address_space(1))) unsigned int*)g,
      (__attribute__((address_space(3))) unsigned int*)l, 16, 0, 0);
}

// ---------------------------------------------------------------------------
// cast x fp32 -> bf16 hi + bf16 lo (split precision)
// ---------------------------------------------------------------------------
__global__ __launch_bounds__(256) void cast_x(const float* __restrict__ x,
                                              unsigned short* __restrict__ xhi,
                                              unsigned short* __restrict__ xlo) {
  int i = (blockIdx.x * 256 + threadIdx.x) * 4;
  float4 v = *(const float4*)&x[i];
  ushort4 h, l;
  h.x = f2bf(v.x); l.x = f2bf(v.x - bf2f(h.x));
  h.y = f2bf(v.y); l.y = f2bf(v.y - bf2f(h.y));
  h.z = f2bf(v.z); l.z = f2bf(v.z - bf2f(h.z));
  h.w = f2bf(v.w); l.w = f2bf(v.w - bf2f(h.w));
  *(ushort4*)&xhi[i] = h;
  *(ushort4*)&xlo[i] = l;
}

// ---------------------------------------------------------------------------
// transpose-cast W [1024][ncols] fp32 -> Wt_hi [ncols][1024] bf16;
// for cols >= locol0 also emit lo residual into Wlo[(col-locol0)][1024].
// ---------------------------------------------------------------------------
__global__ __launch_bounds__(256) void tcast(const float* __restrict__ W,
                                             unsigned short* __restrict__ Wt,
                                             unsigned short* __restrict__ Wlo,
                                             int ncols, int locol0) {
  __shared__ float tile[64][65];
  const int bx = blockIdx.x, by = blockIdx.y, tid = threadIdx.x;
#pragma unroll
  for (int i = 0; i < 16; ++i) {
    int idx = tid + i * 256;
    int r = idx >> 6, c = idx & 63;
    tile[r][c] = W[(size_t)(by * 64 + r) * ncols + bx * 64 + c];
  }
  __syncthreads();
#pragma unroll
  for (int i = 0; i < 16; ++i) {
    int idx = tid + i * 256;
    int r = idx >> 6, c = idx & 63;
    int col = bx * 64 + r;
    float w = tile[c][r];
    unsigned short h = f2bf(w);
    Wt[(size_t)col * 1024 + by * 64 + c] = h;
    if (col >= locol0) {
      Wlo[(size_t)(col - locol0) * 1024 + by * 64 + c] = f2bf(w - bf2f(h));
    }
  }
}

// ---------------------------------------------------------------------------
// 256x256-tile pipelined bf16 GEMM (T2 swizzle + T3/T4 counted vmcnt + T5).
// BK=32. 8 waves (512 thr), wave grid 2(M)x4(N), per-wave output 128x64.
// LDS: 2 buffers x 256 rows x 128B; each row packs [A(r,0..31)|B(r,0..31)]
// bf16 so the full byte ^= ((row&7)<<4) swizzle stays inside the row.
// Staging: global_load_lds w=16 with LINEAR LDS dest; the per-lane GLOBAL
// source carries the inverse swizzle (guide rule 21). For a 1KB store
// covering rows R0..R0+7 (R0%8==0): lane l writes phys (row R0+(l>>3),
// byte (l&7)*16) whose logical content is byte ((l&7)^(l>>3))*16 of the
// packed row -> <64 = A, >=64 = B.
// MODE 0: qk  (N=2048 -> q|k split epilogue, bf16 out)   K=1024
// MODE 1: v   (K=3072 concat: xh@Wh + xl@Wh + xh@Wl, f32 out)
// MODE 2: proj (f32 out, row-major)                      K=1024
// ---------------------------------------------------------------------------
__device__ __forceinline__ void stage256(const unsigned short* __restrict__ Ag,
                                         const unsigned short* __restrict__ Bg,
                                         int row0, int col0, int kin,
                                         unsigned short* lbase, int wave,
                                         int lane) {
  const int rsub = lane >> 3;
  const int logb = ((lane & 7) ^ rsub) << 4;   // 0..112, multiple of 16
  const int isB = logb >> 6;
  const int koff = kin + ((logb & 63) >> 1);   // element offset within K-row
#pragma unroll
  for (int L = 0; L < 4; ++L) {
    const int R0 = (L * 8 + wave) * 8;
    const int r = R0 + rsub;
    const unsigned short* src =
        isB ? (Bg + (size_t)(col0 + r) * 1024 + koff)
            : (Ag + (size_t)(row0 + r) * 1024 + koff);
    gld16(src, lbase + (size_t)R0 * 64);
  }
}

template <int MODE>
__global__ __launch_bounds__(512, 2) void gemm256(
    const unsigned short* __restrict__ A0, const unsigned short* __restrict__ A1,
    const unsigned short* __restrict__ B0, const unsigned short* __restrict__ B1,
    const float* __restrict__ bias, void* __restrict__ out0,
    void* __restrict__ out1) {
  __shared__ __align__(16) unsigned short lds[2][256][64];  // 64 KiB
  const int tid = threadIdx.x;
  const int wave = tid >> 6, lane = tid & 63;
  const int wr = wave >> 2, wc = wave & 3;
  const int m16 = lane & 15, quad = lane >> 4;
  const int row0 = blockIdx.y * 256, col0 = blockIdx.x * 256;
  constexpr int NKT = (MODE == 1) ? 96 : 32;
  f32x4 acc[8][4] = {};

  // prologue: stage tile 0 into buf 0
  stage256(A0, B0, row0, col0, 0, &lds[0][0][0], wave, lane);

  int cur = 0;
  for (int kt = 0; kt < NKT; ++kt) {
    // tile boundary: stage kt+1 into the other buffer (free since kt-1's
    // readers passed the last phase barrier), then wait only for kt's 4
    // loads (issued one full tile ago) -- counted vmcnt, never 0 mid-loop.
    if (kt + 1 < NKT) {
      const unsigned short* Ag = A0;
      const unsigned short* Bg = B0;
      int kin;
      if constexpr (MODE == 1) {
        const int kn = kt + 1, seg = kn >> 5;
        kin = (kn & 31) << 5;
        if (seg == 1) Ag = A1;   // xl @ Wh
        if (seg == 2) Bg = B1;   // xh @ Wl
      } else {
        kin = (kt + 1) << 5;
      }
      stage256(Ag, Bg, row0, col0, kin, &lds[cur ^ 1][0][0], wave, lane);
      asm volatile("s_waitcnt vmcnt(4)" ::: "memory");
    } else {
      asm volatile("s_waitcnt vmcnt(0)" ::: "memory");
    }
    __builtin_amdgcn_s_barrier();

    const char* tb = (const char*)&lds[cur][0][0];
#pragma unroll
    for (int ph = 0; ph < 2; ++ph) {
      bf16x8 af[4], bfr[4];
#pragma unroll
      for (int i = 0; i < 4; ++i) {
        const int r = wr * 128 + (ph * 4 + i) * 16 + m16;
        af[i] = *(const bf16x8*)(tb + r * 128 +
                                 ((quad * 16) ^ ((r & 7) << 4)));
      }
#pragma unroll
      for (int j = 0; j < 4; ++j) {
        const int c = wc * 64 + j * 16 + m16;
        bfr[j] = *(const bf16x8*)(tb + c * 128 +
                                  ((64 + quad * 16) ^ ((c & 7) << 4)));
      }
      __builtin_amdgcn_s_barrier();
      asm volatile("s_waitcnt lgkmcnt(0)" ::: "memory");
      __builtin_amdgcn_sched_barrier(0);
      __builtin_amdgcn_s_setprio(1);
#pragma unroll
      for (int i = 0; i < 4; ++i)
#pragma unroll
        for (int j = 0; j < 4; ++j)
          acc[ph * 4 + i][j] = __builtin_amdgcn_mfma_f32_16x16x32_bf16(
              af[i], bfr[j], acc[ph * 4 + i][j], 0, 0, 0);
      __builtin_amdgcn_s_setprio(0);
      __builtin_amdgcn_s_barrier();
    }
    cur ^= 1;
  }

  if constexpr (MODE == 0) {
    unsigned short* dst = (col0 >= 1024) ? (unsigned short*)out1
                                         : (unsigned short*)out0;
#pragma unroll
    for (int j = 0; j < 4; ++j) {
      const int gcol = col0 + wc * 64 + j * 16 + m16;
      const int f = gcol & 1023;
      const int h = f >> 6, dd = f & 63;
      const float bv = bias[gcol];
#pragma unroll
      for (int i = 0; i < 8; ++i) {
#pragma unroll
        for (int r = 0; r < 4; ++r) {
          const int grow = row0 + wr * 128 + i * 16 + quad * 4 + r;
          const int b = grow >> 10, t = grow & 1023;
          dst[(((size_t)b * H + h) * T + t) * D + dd] = f2bf(acc[i][j][r] + bv);
        }
      }
    }
  } else if constexpr (MODE == 1) {
    float* vbp = (float*)out0;
#pragma unroll
    for (int j = 0; j < 4; ++j) {
      const int f = col0 + wc * 64 + j * 16 + m16;
      const int h = f >> 6, dd = f & 63;
      const float bv = bias[f];
#pragma unroll
      for (int i = 0; i < 8; ++i) {
#pragma unroll
        for (int r = 0; r < 4; ++r) {
          const int grow = row0 + wr * 128 + i * 16 + quad * 4 + r;
          const int b = grow >> 10, t = grow & 1023;
          vbp[(((size_t)b * H + h) * T + t) * D + dd] = acc[i][j][r] + bv;
        }
      }
    }
  } else {
    float* o = (float*)out0;
#pragma unroll
    for (int j = 0; j < 4; ++j) {
      const int gcol = col0 + wc * 64 + j * 16 + m16;
      const float bv = bias[gcol];
#pragma unroll
      for (int i = 0; i < 8; ++i) {
#pragma unroll
        for (int r = 0; r < 4; ++r) {
          const int grow = row0 + wr * 128 + i * 16 + quad * 4 + r;
          o[(size_t)grow * F + gcol] = acc[i][j][r] + bv;
        }
      }
    }
  }
}

// ---------------------------------------------------------------------------
// s[b,h,d,e] = sum_t q[t,d]*k[t,e] / 8, tril-masked. q,k bf16.
// ---------------------------------------------------------------------------
__global__ __launch_bounds__(256) void score_kernel(
    const unsigned short* __restrict__ qb, const unsigned short* __restrict__ kb,
    float* __restrict__ sb) {
  __shared__ float qs[64][65];
  __shared__ float ks[64][65];
  const int bh = blockIdx.x;
  const int tid = threadIdx.x;
  const size_t base = (size_t)bh * T * D;
  const int d0 = (tid >> 4) * 4, e0 = (tid & 15) * 4;
  float acc[4][4] = {};
  for (int ch = 0; ch < T / 64; ++ch) {
#pragma unroll
    for (int i = 0; i < 4; ++i) {
      int idx = (tid + i * 256) * 4;
      ushort4 qv = *(const ushort4*)&qb[base + (size_t)ch * 4096 + idx];
      ushort4 kv = *(const ushort4*)&kb[base + (size_t)ch * 4096 + idx];
      int r = idx >> 6, c = idx & 63;
      qs[r][c] = bf2f(qv.x); qs[r][c+1] = bf2f(qv.y);
      qs[r][c+2] = bf2f(qv.z); qs[r][c+3] = bf2f(qv.w);
      ks[r][c] = bf2f(kv.x); ks[r][c+1] = bf2f(kv.y);
      ks[r][c+2] = bf2f(kv.z); ks[r][c+3] = bf2f(kv.w);
    }
    __syncthreads();
#pragma unroll 8
    for (int tt = 0; tt < 64; ++tt) {
      float qa[4], kv[4];
#pragma unroll
      for (int i = 0; i < 4; ++i) qa[i] = qs[tt][d0 + i];
#pragma unroll
      for (int j = 0; j < 4; ++j) kv[j] = ks[tt][e0 + j];
#pragma unroll
      for (int i = 0; i < 4; ++i)
#pragma unroll
        for (int j = 0; j < 4; ++j) acc[i][j] += qa[i] * kv[j];
    }
    __syncthreads();
  }
#pragma unroll
  for (int i = 0; i < 4; ++i) {
#pragma unroll
    for (int j = 0; j < 4; ++j) {
      int dd = d0 + i, ee = e0 + j;
      float v = acc[i][j] * 0.125f;
      if (ee > dd) v = -10000.0f;
      sb[(size_t)bh * (D * D) + dd * D + ee] = v;
    }
  }
}

// ---------------------------------------------------------------------------
// exp_kernel: grid (tc, bh). thread = (lane=t within chunk, wave=dgroup).
// w[t,d] = (s[d,:].v[t,:])/4096 + mask[b,t];  e = exp(w) (no-max: |w|<~80 safe)
// writes e to wraw[bh][d][t] (transposed, coalesced) + per-(block,d) partial
// sums to sp[bh][tc][d]. v row held in VGPRs; s row is wave-uniform -> SGPRs.
// ---------------------------------------------------------------------------
__global__ __launch_bounds__(256) void exp_kernel(
    const float* __restrict__ vb, const float* __restrict__ sb,
    const float* __restrict__ mask, float* __restrict__ wraw,
    float* __restrict__ sp) {
  const int tc = blockIdx.x, bh = blockIdx.y;
  const int b = bh >> 4;
  const int tid = threadIdx.x;
  const int lane = tid & 63;
  const int dg = __builtin_amdgcn_readfirstlane(tid >> 6);
  const int tg = tc * 64 + lane;
  const float* vrow = vb + (size_t)bh * (T * D) + (size_t)tg * D;
  float4 vreg[16];
#pragma unroll
  for (int i = 0; i < 16; ++i) vreg[i] = *(const float4*)&vrow[i * 4];
  const float mval = mask[(size_t)b * T + tg];
  float ex[16];
#pragma unroll
  for (int dd = 0; dd < 16; ++dd) {
    const int d = dg * 16 + dd;
    const float* srow = sb + (size_t)bh * 4096 + (size_t)d * 64;
    float acc = 0.f;
#pragma unroll
    for (int e4 = 0; e4 < 16; ++e4) {
      float4 s4 = *(const float4*)&srow[e4 * 4];
      acc += s4.x * vreg[e4].x + s4.y * vreg[e4].y +
             s4.z * vreg[e4].z + s4.w * vreg[e4].w;
    }
    float w = acc * (1.0f / 4096.0f) + mval;
    ex[dd] = __expf(w);
    wraw[(size_t)bh * (T * D) + (size_t)d * T + tg] = ex[dd];
  }
  // per-wave (per-d) sum over the 64 t-lanes, deterministic butterfly
#pragma unroll
  for (int dd = 0; dd < 16; ++dd) {
    float v = ex[dd];
    v += __shfl_xor(v, 1, 64);
    v += __shfl_xor(v, 2, 64);
    v += __shfl_xor(v, 4, 64);
    v += __shfl_xor(v, 8, 64);
    v += __shfl_xor(v, 16, 64);
    v += __shfl_xor(v, 32, 64);
    if (lane == 0) sp[((size_t)bh * 16 + tc) * 64 + dg * 16 + dd] = v;
  }
}

// ---------------------------------------------------------------------------
// norm_kernel: grid (tc, bh). Reduce partials -> 1/S; stage wraw chunk via
// LDS (transpose back); write out2 = e/S and ab = bf16((e/S)*v), coalesced.
// ---------------------------------------------------------------------------
__global__ __launch_bounds__(256) void norm_kernel(
    const float* __restrict__ vb, const float* __restrict__ wraw,
    const float* __restrict__ sp, unsigned short* __restrict__ ab,
    float* __restrict__ out2) {
  __shared__ float wt[64][65];
  __shared__ float invS[64];
  const int tc = blockIdx.x, bh = blockIdx.y;
  const int b = bh >> 4, h = bh & 15;
  const int tid = threadIdx.x;
  if (tid < 64) {
    float S = 0.f;
#pragma unroll
    for (int j = 0; j < 16; ++j) S += sp[((size_t)bh * 16 + j) * 64 + tid];
    invS[tid] = 1.0f / S;
  }
#pragma unroll
  for (int i = 0; i < 16; ++i) {
    int idx = tid + i * 256;
    int dd = idx >> 6, tt = idx & 63;
    wt[dd][tt] = wraw[(size_t)bh * (T * D) + (size_t)dd * T + tc * 64 + tt];
  }
  __syncthreads();
  const int d = tid & 63, trow = tid >> 6;
#pragma unroll
  for (int j = 0; j < 16; ++j) {
    int tl = trow * 16 + j;
    int tg = tc * 64 + tl;
    float o = wt[d][tl] * invS[d];
    float vv = vb[(size_t)bh * (T * D) + (size_t)tg * D + d];
    size_t oidx = ((size_t)b * T + tg) * F + h * 64 + d;
    out2[oidx] = o;
    ab[oidx] = f2bf(o * vv);
  }
}

extern "C" void kernel_launch(void* const* d_in, const int* in_sizes, int n_in,
                              void* d_out, int out_size, void* d_ws,
                              size_t ws_size, hipStream_t stream) {
  const float* x = (const float*)d_in[0];
  const float* mask = (const float*)d_in[1];
  const float* Wa = (const float*)d_in[2];
  const float* ba = (const float*)d_in[3];
  const float* Wp = (const float*)d_in[4];
  const float* bp = (const float*)d_in[5];
  char* ws = (char*)d_ws;
  float* out = (float*)d_out;

  unsigned short* xhi = (unsigned short*)(ws + XHI_OFF);
  unsigned short* xlo = (unsigned short*)(ws + XLO_OFF);
  unsigned short* Wah = (unsigned short*)(ws + WAH_OFF);
  unsigned short* Wvl = (unsigned short*)(ws + WVL_OFF);
  unsigned short* qb  = (unsigned short*)(ws + QB_OFF);
  unsigned short* kb  = (unsigned short*)(ws + KB_OFF);
  float* sb   = (float*)(ws + SB_OFF);
  unsigned short* ab  = (unsigned short*)(ws + AB_OFF);
  unsigned short* Wpb = (unsigned short*)(ws + WPB_OFF);
  float* vb   = (float*)(ws + VB_OFF);     // overlays q,k (dead after score)
  float* wraw = (float*)(ws + WRAW_OFF);   // overlays x hi/lo (dead after v)
  float* sp   = (float*)(ws + SP_OFF);     // overlays Wv_lo (dead after v)

  cast_x<<<NT * F / 1024, 256, 0, stream>>>(x, xhi, xlo);
  tcast<<<dim3(QKV_COLS / 64, F / 64), 256, 0, stream>>>(Wa, Wah, Wvl,
                                                         QKV_COLS, 2048);
  tcast<<<dim3(F / 64, F / 64), 256, 0, stream>>>(Wp, Wpb, Wvl, F, 1 << 30);

  // q,k GEMM: N=2048, K=1024
  gemm256<0><<<dim3(2048 / 256, NT / 256), 512, 0, stream>>>(
      xhi, nullptr, Wah, nullptr, ba, qb, kb);

  score_kernel<<<dim3(B * H), 256, 0, stream>>>(qb, kb, sb);

  // v GEMM (q,k now dead -> vb overlays them): K=3072 concat of
  // xh@Wvh + xl@Wvh + xh@Wvl, fp32 out.
  gemm256<1><<<dim3(F / 256, NT / 256), 512, 0, stream>>>(
      xhi, xlo, Wah + (size_t)2048 * 1024, Wvl, ba + 2048, vb, nullptr);

  exp_kernel<<<dim3(T / 64, B * H), 256, 0, stream>>>(vb, sb, mask, wraw, sp);

  norm_kernel<<<dim3(T / 64, B * H), 256, 0, stream>>>(
      vb, wraw, sp, ab, out + (size_t)NT * F);

  // proj GEMM: N=1024, K=1024
  gemm256<2><<<dim3(F / 256, NT / 256), 512, 0, stream>>>(
      ab, nullptr, Wpb, nullptr, bp, out, nullptr);
}

// Round 2
// 630.333 us; speedup vs baseline: 1.2055x; 1.0128x over previous
//
#include <hip/hip_runtime.h>
#include <math.h>

namespace {
constexpr int B = 16, T = 1024, F = 1024, H = 16, D = 64;
constexpr int NT = B * T;            // 16384 token rows
constexpr int QKV_COLS = 3 * F;      // 3072

// workspace layout (bytes). Proven ws_size >= 182,452,224.
constexpr size_t XHI_OFF = 0;                    // bf16 x hi      33,554,432
constexpr size_t XLO_OFF = 33554432;             // bf16 x lo      33,554,432
constexpr size_t WAH_OFF = 67108864;             // bf16 Wa^T hi    6,291,456
constexpr size_t WVL_OFF = 73400320;             // bf16 Wv^T lo    2,097,152
constexpr size_t QB_OFF  = 75497472;             // bf16 q         33,554,432
constexpr size_t KB_OFF  = 109051904;            // bf16 k         33,554,432
constexpr size_t SB_OFF  = 142606336;            // f32 s           4,194,304
constexpr size_t AB_OFF  = 146800640;            // bf16 a         33,554,432
constexpr size_t WPB_OFF = 180355072;            // bf16 Wp^T       2,097,152
// overlays: vb (f32, 67MB) = QB..KB span (q,k dead after score);
//           wraw (f32, 67MB) = XHI..XLO span (x dead after v GEMM);
//           sp partial sums (f32, 256KB) = WVL span (Wv_lo dead after v GEMM)
constexpr size_t VB_OFF   = QB_OFF;
constexpr size_t WRAW_OFF = XHI_OFF;
constexpr size_t SP_OFF   = WVL_OFF;
}

typedef __attribute__((ext_vector_type(8))) __bf16 bf16x8;
typedef __attribute__((ext_vector_type(4))) float f32x4;

__device__ __forceinline__ unsigned short f2bf(float f) {
  unsigned u = __builtin_bit_cast(unsigned, f);
  u += 0x7FFFu + ((u >> 16) & 1u);
  return (unsigned short)(u >> 16);
}
__device__ __forceinline__ float bf2f(unsigned short s) {
  return __builtin_bit_cast(float, (unsigned)s << 16);
}
__device__ __forceinline__ void gld16(const unsigned short* g, unsigned short* l) {
  __builtin_amdgcn_global_load_lds(
      (const __attribute__((address_space(1))) unsigned int*)g,
      (__attribute__((address_space(3))) unsigned int*)l, 16, 0, 0);
}

// ---------------------------------------------------------------------------
// cast x fp32 -> bf16 hi + bf16 lo (split precision)
// ---------------------------------------------------------------------------
__global__ __launch_bounds__(256) void cast_x(const float* __restrict__ x,
                                              unsigned short* __restrict__ xhi,
                                              unsigned short* __restrict__ xlo) {
  int i = (blockIdx.x * 256 + threadIdx.x) * 4;
  float4 v = *(const float4*)&x[i];
  ushort4 h, l;
  h.x = f2bf(v.x); l.x = f2bf(v.x - bf2f(h.x));
  h.y = f2bf(v.y); l.y = f2bf(v.y - bf2f(h.y));
  h.z = f2bf(v.z); l.z = f2bf(v.z - bf2f(h.z));
  h.w = f2bf(v.w); l.w = f2bf(v.w - bf2f(h.w));
  *(ushort4*)&xhi[i] = h;
  *(ushort4*)&xlo[i] = l;
}

// ---------------------------------------------------------------------------
// transpose-cast W [1024][ncols] fp32 -> Wt_hi [ncols][1024] bf16;
// for cols >= locol0 also emit lo residual into Wlo[(col-locol0)][1024].
// ---------------------------------------------------------------------------
__global__ __launch_bounds__(256) void tcast(const float* __restrict__ W,
                                             unsigned short* __restrict__ Wt,
                                             unsigned short* __restrict__ Wlo,
                                             int ncols, int locol0) {
  __shared__ float tile[64][65];
  const int bx = blockIdx.x, by = blockIdx.y, tid = threadIdx.x;
#pragma unroll
  for (int i = 0; i < 16; ++i) {
    int idx = tid + i * 256;
    int r = idx >> 6, c = idx & 63;
    tile[r][c] = W[(size_t)(by * 64 + r) * ncols + bx * 64 + c];
  }
  __syncthreads();
#pragma unroll
  for (int i = 0; i < 16; ++i) {
    int idx = tid + i * 256;
    int r = idx >> 6, c = idx & 63;
    int col = bx * 64 + r;
    float w = tile[c][r];
    unsigned short h = f2bf(w);
    Wt[(size_t)col * 1024 + by * 64 + c] = h;
    if (col >= locol0) {
      Wlo[(size_t)(col - locol0) * 1024 + by * 64 + c] = f2bf(w - bf2f(h));
    }
  }
}

// ---------------------------------------------------------------------------
// 256x256-tile pipelined bf16 GEMM, prefetch depth 3 (T2+T3/T4+T5).
// BK=32. 8 waves (512 thr), wave grid 2(M)x4(N), per-wave output 128x64.
// LDS: 4 buffers x 256 rows x 128B; each row packs [A(r,k..k+31)|B(r,k..k+31)]
// bf16 so the byte ^= ((row&7)<<4) swizzle stays inside the row (measured
// SQ_LDS_BANK_CONFLICT == 0 with this layout).
// Staging: global_load_lds w=16 with LINEAR LDS dest; the per-lane GLOBAL
// source carries the inverse swizzle (guide rule 21).
// Pipeline: at tile kt, issue tile kt+3's 4 loads into buf[(kt+3)&3], then
// s_waitcnt vmcnt(12) -> drains ONLY tile kt's 4 loads (issued ~3 tile-walls
// ago, >1200cy: covers L2~200cy / HBM~900cy latency). 2 barriers per tile.
// MODE 0: qk  (N=2048 -> q|k split epilogue, bf16 out)   K=1024
// MODE 1: v   (K=3072 concat: xh@Wh + xl@Wh + xh@Wl, f32 out)
// MODE 2: proj (f32 out, row-major)                      K=1024
// ---------------------------------------------------------------------------
__device__ __forceinline__ void stage256(const unsigned short* __restrict__ Ag,
                                         const unsigned short* __restrict__ Bg,
                                         int row0, int col0, int kin,
                                         unsigned short* lbase, int wave,
                                         int lane) {
  const int rsub = lane >> 3;
  const int logb = ((lane & 7) ^ rsub) << 4;   // 0..112, multiple of 16
  const int isB = logb >> 6;
  const int koff = kin + ((logb & 63) >> 1);   // element offset within K-row
#pragma unroll
  for (int L = 0; L < 4; ++L) {
    const int R0 = (L * 8 + wave) * 8;
    const int r = R0 + rsub;
    const unsigned short* src =
        isB ? (Bg + (size_t)(col0 + r) * 1024 + koff)
            : (Ag + (size_t)(row0 + r) * 1024 + koff);
    gld16(src, lbase + (size_t)R0 * 64);
  }
}

template <int MODE>
__device__ __forceinline__ void tile_src(
    int kt, const unsigned short* __restrict__ A0,
    const unsigned short* __restrict__ A1,
    const unsigned short* __restrict__ B0,
    const unsigned short* __restrict__ B1,
    const unsigned short*& Ag, const unsigned short*& Bg, int& kin) {
  if constexpr (MODE == 1) {
    const int seg = kt >> 5;
    kin = (kt & 31) << 5;
    Ag = (seg == 1) ? A1 : A0;   // seg1: xl @ Wh
    Bg = (seg == 2) ? B1 : B0;   // seg2: xh @ Wl
  } else {
    Ag = A0; Bg = B0; kin = kt << 5;
  }
}

template <int MODE>
__global__ __launch_bounds__(512, 2) void gemm256(
    const unsigned short* __restrict__ A0, const unsigned short* __restrict__ A1,
    const unsigned short* __restrict__ B0, const unsigned short* __restrict__ B1,
    const float* __restrict__ bias, void* __restrict__ out0,
    void* __restrict__ out1) {
  __shared__ __align__(16) unsigned short lds[4][256][64];  // 128 KiB
  const int tid = threadIdx.x;
  const int wave = tid >> 6, lane = tid & 63;
  const int wr = wave >> 2, wc = wave & 3;
  const int m16 = lane & 15, quad = lane >> 4;
  const int row0 = blockIdx.y * 256, col0 = blockIdx.x * 256;
  constexpr int NKT = (MODE == 1) ? 96 : 32;
  f32x4 acc[8][4] = {};

  // prologue: stage tiles 0,1,2 into buffers 0,1,2 (12 loads in flight)
#pragma unroll
  for (int p = 0; p < 3; ++p) {
    const unsigned short *Ag, *Bg; int kin;
    tile_src<MODE>(p, A0, A1, B0, B1, Ag, Bg, kin);
    stage256(Ag, Bg, row0, col0, kin, &lds[p][0][0], wave, lane);
  }

  for (int kt = 0; kt < NKT; ++kt) {
    if (kt + 3 < NKT) {
      const unsigned short *Ag, *Bg; int kin;
      tile_src<MODE>(kt + 3, A0, A1, B0, B1, Ag, Bg, kin);
      stage256(Ag, Bg, row0, col0, kin, &lds[(kt + 3) & 3][0][0], wave, lane);
      asm volatile("s_waitcnt vmcnt(12)" ::: "memory");
    } else {
      const int rem = NKT - 1 - kt;  // 2,1,0
      if (rem == 2)      asm volatile("s_waitcnt vmcnt(8)" ::: "memory");
      else if (rem == 1) asm volatile("s_waitcnt vmcnt(4)" ::: "memory");
      else               asm volatile("s_waitcnt vmcnt(0)" ::: "memory");
    }
    __builtin_amdgcn_s_barrier();            // buf[kt&3] fully staged
    __builtin_amdgcn_sched_barrier(0);       // no ds_read hoisting above

    const char* tb = (const char*)&lds[kt & 3][0][0];
    bf16x8 bfr[4], af0[4], af1[4];
#pragma unroll
    for (int j = 0; j < 4; ++j) {
      const int c = wc * 64 + j * 16 + m16;
      bfr[j] = *(const bf16x8*)(tb + c * 128 +
                                ((64 + quad * 16) ^ ((c & 7) << 4)));
    }
#pragma unroll
    for (int i = 0; i < 4; ++i) {
      const int r = wr * 128 + i * 16 + m16;
      af0[i] = *(const bf16x8*)(tb + r * 128 +
                                ((quad * 16) ^ ((r & 7) << 4)));
    }
#pragma unroll
    for (int i = 0; i < 4; ++i) {
      const int r = wr * 128 + 64 + i * 16 + m16;
      af1[i] = *(const bf16x8*)(tb + r * 128 +
                                ((quad * 16) ^ ((r & 7) << 4)));
    }
    __builtin_amdgcn_s_setprio(1);
#pragma unroll
    for (int i = 0; i < 4; ++i)
#pragma unroll
      for (int j = 0; j < 4; ++j)
        acc[i][j] = __builtin_amdgcn_mfma_f32_16x16x32_bf16(
            af0[i], bfr[j], acc[i][j], 0, 0, 0);
#pragma unroll
    for (int i = 0; i < 4; ++i)
#pragma unroll
      for (int j = 0; j < 4; ++j)
        acc[4 + i][j] = __builtin_amdgcn_mfma_f32_16x16x32_bf16(
            af1[i], bfr[j], acc[4 + i][j], 0, 0, 0);
    __builtin_amdgcn_s_setprio(0);
    __builtin_amdgcn_s_barrier();            // all reads of buf[kt&3] done
    __builtin_amdgcn_sched_barrier(0);       // no staging hoisting above
  }

  if constexpr (MODE == 0) {
    unsigned short* dst = (col0 >= 1024) ? (unsigned short*)out1
                                         : (unsigned short*)out0;
#pragma unroll
    for (int j = 0; j < 4; ++j) {
      const int gcol = col0 + wc * 64 + j * 16 + m16;
      const int f = gcol & 1023;
      const int h = f >> 6, dd = f & 63;
      const float bv = bias[gcol];
#pragma unroll
      for (int i = 0; i < 8; ++i) {
#pragma unroll
        for (int r = 0; r < 4; ++r) {
          const int grow = row0 + wr * 128 + i * 16 + quad * 4 + r;
          const int b = grow >> 10, t = grow & 1023;
          dst[(((size_t)b * H + h) * T + t) * D + dd] = f2bf(acc[i][j][r] + bv);
        }
      }
    }
  } else if constexpr (MODE == 1) {
    float* vbp = (float*)out0;
#pragma unroll
    for (int j = 0; j < 4; ++j) {
      const int f = col0 + wc * 64 + j * 16 + m16;
      const int h = f >> 6, dd = f & 63;
      const float bv = bias[f];
#pragma unroll
      for (int i = 0; i < 8; ++i) {
#pragma unroll
        for (int r = 0; r < 4; ++r) {
          const int grow = row0 + wr * 128 + i * 16 + quad * 4 + r;
          const int b = grow >> 10, t = grow & 1023;
          vbp[(((size_t)b * H + h) * T + t) * D + dd] = acc[i][j][r] + bv;
        }
      }
    }
  } else {
    float* o = (float*)out0;
#pragma unroll
    for (int j = 0; j < 4; ++j) {
      const int gcol = col0 + wc * 64 + j * 16 + m16;
      const float bv = bias[gcol];
#pragma unroll
      for (int i = 0; i < 8; ++i) {
#pragma unroll
        for (int r = 0; r < 4; ++r) {
          const int grow = row0 + wr * 128 + i * 16 + quad * 4 + r;
          o[(size_t)grow * F + gcol] = acc[i][j][r] + bv;
        }
      }
    }
  }
}

// ---------------------------------------------------------------------------
// s[b,h,d,e] = sum_t q[t,d]*k[t,e] / 8, tril-masked. q,k bf16.
// ---------------------------------------------------------------------------
__global__ __launch_bounds__(256) void score_kernel(
    const unsigned short* __restrict__ qb, const unsigned short* __restrict__ kb,
    float* __restrict__ sb) {
  __shared__ float qs[64][65];
  __shared__ float ks[64][65];
  const int bh = blockIdx.x;
  const int tid = threadIdx.x;
  const size_t base = (size_t)bh * T * D;
  const int d0 = (tid >> 4) * 4, e0 = (tid & 15) * 4;
  float acc[4][4] = {};
  for (int ch = 0; ch < T / 64; ++ch) {
#pragma unroll
    for (int i = 0; i < 4; ++i) {
      int idx = (tid + i * 256) * 4;
      ushort4 qv = *(const ushort4*)&qb[base + (size_t)ch * 4096 + idx];
      ushort4 kv = *(const ushort4*)&kb[base + (size_t)ch * 4096 + idx];
      int r = idx >> 6, c = idx & 63;
      qs[r][c] = bf2f(qv.x); qs[r][c+1] = bf2f(qv.y);
      qs[r][c+2] = bf2f(qv.z); qs[r][c+3] = bf2f(qv.w);
      ks[r][c] = bf2f(kv.x); ks[r][c+1] = bf2f(kv.y);
      ks[r][c+2] = bf2f(kv.z); ks[r][c+3] = bf2f(kv.w);
    }
    __syncthreads();
#pragma unroll 8
    for (int tt = 0; tt < 64; ++tt) {
      float qa[4], kv[4];
#pragma unroll
      for (int i = 0; i < 4; ++i) qa[i] = qs[tt][d0 + i];
#pragma unroll
      for (int j = 0; j < 4; ++j) kv[j] = ks[tt][e0 + j];
#pragma unroll
      for (int i = 0; i < 4; ++i)
#pragma unroll
        for (int j = 0; j < 4; ++j) acc[i][j] += qa[i] * kv[j];
    }
    __syncthreads();
  }
#pragma unroll
  for (int i = 0; i < 4; ++i) {
#pragma unroll
    for (int j = 0; j < 4; ++j) {
      int dd = d0 + i, ee = e0 + j;
      float v = acc[i][j] * 0.125f;
      if (ee > dd) v = -10000.0f;
      sb[(size_t)bh * (D * D) + dd * D + ee] = v;
    }
  }
}

// ---------------------------------------------------------------------------
// exp_kernel: grid (tc, bh). thread = (lane=t within chunk, wave=dgroup).
// w[t,d] = (s[d,:].v[t,:])/4096 + mask[b,t];  e = exp(w) (no-max: |w|<~80 safe)
// writes e to wraw[bh][d][t] (transposed, coalesced) + per-(block,d) partial
// sums to sp[bh][tc][d]. v row held in VGPRs; s row is wave-uniform -> SGPRs.
// ---------------------------------------------------------------------------
__global__ __launch_bounds__(256) void exp_kernel(
    const float* __restrict__ vb, const float* __restrict__ sb,
    const float* __restrict__ mask, float* __restrict__ wraw,
    float* __restrict__ sp) {
  const int tc = blockIdx.x, bh = blockIdx.y;
  const int b = bh >> 4;
  const int tid = threadIdx.x;
  const int lane = tid & 63;
  const int dg = __builtin_amdgcn_readfirstlane(tid >> 6);
  const int tg = tc * 64 + lane;
  const float* vrow = vb + (size_t)bh * (T * D) + (size_t)tg * D;
  float4 vreg[16];
#pragma unroll
  for (int i = 0; i < 16; ++i) vreg[i] = *(const float4*)&vrow[i * 4];
  const float mval = mask[(size_t)b * T + tg];
  float ex[16];
#pragma unroll
  for (int dd = 0; dd < 16; ++dd) {
    const int d = dg * 16 + dd;
    const float* srow = sb + (size_t)bh * 4096 + (size_t)d * 64;
    float acc = 0.f;
#pragma unroll
    for (int e4 = 0; e4 < 16; ++e4) {
      float4 s4 = *(const float4*)&srow[e4 * 4];
      acc += s4.x * vreg[e4].x + s4.y * vreg[e4].y +
             s4.z * vreg[e4].z + s4.w * vreg[e4].w;
    }
    float w = acc * (1.0f / 4096.0f) + mval;
    ex[dd] = __expf(w);
    wraw[(size_t)bh * (T * D) + (size_t)d * T + tg] = ex[dd];
  }
  // per-wave (per-d) sum over the 64 t-lanes, deterministic butterfly
#pragma unroll
  for (int dd = 0; dd < 16; ++dd) {
    float v = ex[dd];
    v += __shfl_xor(v, 1, 64);
    v += __shfl_xor(v, 2, 64);
    v += __shfl_xor(v, 4, 64);
    v += __shfl_xor(v, 8, 64);
    v += __shfl_xor(v, 16, 64);
    v += __shfl_xor(v, 32, 64);
    if (lane == 0) sp[((size_t)bh * 16 + tc) * 64 + dg * 16 + dd] = v;
  }
}

// ---------------------------------------------------------------------------
// norm_kernel: grid (tc, bh). Reduce partials -> 1/S; stage wraw chunk via
// LDS (transpose back); write out2 = e/S and ab = bf16((e/S)*v), coalesced.
// ---------------------------------------------------------------------------
__global__ __launch_bounds__(256) void norm_kernel(
    const float* __restrict__ vb, const float* __restrict__ wraw,
    const float* __restrict__ sp, unsigned short* __restrict__ ab,
    float* __restrict__ out2) {
  __shared__ float wt[64][65];
  __shared__ float invS[64];
  const int tc = blockIdx.x, bh = blockIdx.y;
  const int b = bh >> 4, h = bh & 15;
  const int tid = threadIdx.x;
  if (tid < 64) {
    float S = 0.f;
#pragma unroll
    for (int j = 0; j < 16; ++j) S += sp[((size_t)bh * 16 + j) * 64 + tid];
    invS[tid] = 1.0f / S;
  }
#pragma unroll
  for (int i = 0; i < 16; ++i) {
    int idx = tid + i * 256;
    int dd = idx >> 6, tt = idx & 63;
    wt[dd][tt] = wraw[(size_t)bh * (T * D) + (size_t)dd * T + tc * 64 + tt];
  }
  __syncthreads();
  const int d = tid & 63, trow = tid >> 6;
#pragma unroll
  for (int j = 0; j < 16; ++j) {
    int tl = trow * 16 + j;
    int tg = tc * 64 + tl;
    float o = wt[d][tl] * invS[d];
    float vv = vb[(size_t)bh * (T * D) + (size_t)tg * D + d];
    size_t oidx = ((size_t)b * T + tg) * F + h * 64 + d;
    out2[oidx] = o;
    ab[oidx] = f2bf(o * vv);
  }
}

extern "C" void kernel_launch(void* const* d_in, const int* in_sizes, int n_in,
                              void* d_out, int out_size, void* d_ws,
                              size_t ws_size, hipStream_t stream) {
  const float* x = (const float*)d_in[0];
  const float* mask = (const float*)d_in[1];
  const float* Wa = (const float*)d_in[2];
  const float* ba = (const float*)d_in[3];
  const float* Wp = (const float*)d_in[4];
  const float* bp = (const float*)d_in[5];
  char* ws = (char*)d_ws;
  float* out = (float*)d_out;

  unsigned short* xhi = (unsigned short*)(ws + XHI_OFF);
  unsigned short* xlo = (unsigned short*)(ws + XLO_OFF);
  unsigned short* Wah = (unsigned short*)(ws + WAH_OFF);
  unsigned short* Wvl = (unsigned short*)(ws + WVL_OFF);
  unsigned short* qb  = (unsigned short*)(ws + QB_OFF);
  unsigned short* kb  = (unsigned short*)(ws + KB_OFF);
  float* sb   = (float*)(ws + SB_OFF);
  unsigned short* ab  = (unsigned short*)(ws + AB_OFF);
  unsigned short* Wpb = (unsigned short*)(ws + WPB_OFF);
  float* vb   = (float*)(ws + VB_OFF);     // overlays q,k (dead after score)
  float* wraw = (float*)(ws + WRAW_OFF);   // overlays x hi/lo (dead after v)
  float* sp   = (float*)(ws + SP_OFF);     // overlays Wv_lo (dead after v)

  cast_x<<<NT * F / 1024, 256, 0, stream>>>(x, xhi, xlo);
  tcast<<<dim3(QKV_COLS / 64, F / 64), 256, 0, stream>>>(Wa, Wah, Wvl,
                                                         QKV_COLS, 2048);
  tcast<<<dim3(F / 64, F / 64), 256, 0, stream>>>(Wp, Wpb, Wvl, F, 1 << 30);

  // q,k GEMM: N=2048, K=1024
  gemm256<0><<<dim3(2048 / 256, NT / 256), 512, 0, stream>>>(
      xhi, nullptr, Wah, nullptr, ba, qb, kb);

  score_kernel<<<dim3(B * H), 256, 0, stream>>>(qb, kb, sb);

  // v GEMM (q,k now dead -> vb overlays them): K=3072 concat of
  // xh@Wvh + xl@Wvh + xh@Wvl, fp32 out.
  gemm256<1><<<dim3(F / 256, NT / 256), 512, 0, stream>>>(
      xhi, xlo, Wah + (size_t)2048 * 1024, Wvl, ba + 2048, vb, nullptr);

  exp_kernel<<<dim3(T / 64, B * H), 256, 0, stream>>>(vb, sb, mask, wraw, sp);

  norm_kernel<<<dim3(T / 64, B * H), 256, 0, stream>>>(
      vb, wraw, sp, ab, out + (size_t)NT * F);

  // proj GEMM: N=1024, K=1024
  gemm256<2><<<dim3(F / 256, NT / 256), 512, 0, stream>>>(
      ab, nullptr, Wpb, nullptr, bp, out, nullptr);
}